// Round 2
// baseline (245.728 us; speedup 1.0000x reference)
//
#include <hip/hip_runtime.h>
#include <cstddef>
#include <cstdint>

// Problem constants (fixed by reference file)
#define B_     256
#define V_     128000
#define T_     16
#define TOPK_  100
#define CAP    4096
#define NF4    (V_ / 4)      // 32000 float4 per row
#define NHIST  4096
#define SLICES 8
#define F4S    (NF4 / SLICES)  // 4000 float4 per slice
#define T0     0.998f          // expected ~256 candidates/row (sigma ~16)

// ws layout: [0, 1024)   : int ws_cnt[B_]      (256*4 = 1024 B)
//            [4096, ...) : float ws_cand[B_][CAP]  (4 MB)
// ws_size is hundreds of MB per the harness fills — ample.

__global__ void zero_kernel(float* o, int* ws_cnt) {
    int t = threadIdx.x;
    if (t < 3) o[t] = 0.f;
    if (t < B_) ws_cnt[t] = 0;
}

// Kernel A: pure streaming collect. 2048 blocks x 256 threads.
__global__ __launch_bounds__(256) void collect_kernel(
        const float* __restrict__ sparse,
        const int*   __restrict__ tids,
        float*       __restrict__ ws_cand,
        int*         __restrict__ ws_cnt) {
    __shared__ int s_ids[T_];
    const int blk = blockIdx.x;
    const int row = blk >> 3;          // / SLICES
    const int sl  = blk & (SLICES - 1);
    const int tid = threadIdx.x;
    if (tid < T_) s_ids[tid] = tids[row * T_ + tid];
    __syncthreads();

    const float4* __restrict__ rp4 = (const float4*)(sparse + (size_t)row * V_);
    float* __restrict__ cand = ws_cand + (size_t)row * CAP;
    int*   cntp = ws_cnt + row;

    const int i0 = sl * F4S;
    for (int i = i0 + tid; i < i0 + F4S; i += 256) {
        float4 v = rp4[i];
        int col = i << 2;
        float xs[4] = {v.x, v.y, v.z, v.w};
        #pragma unroll
        for (int c = 0; c < 4; ++c) {
            float x = xs[c];
            if (x >= T0) {
                int cc = col + c;
                bool is_t = false;
                #pragma unroll
                for (int j = 0; j < T_; ++j) is_t |= (cc == s_ids[j]);
                if (!is_t) {
                    int k = atomicAdd(cntp, 1);
                    if (k < CAP) cand[k] = x;
                }
            }
        }
    }
}

// Kernel B: per-row top-100 sum via O(n^2) rank-select + target/margin losses.
__global__ __launch_bounds__(256) void reduce_kernel(
        const float* __restrict__ sparse,
        const int*   __restrict__ tids,
        const float* __restrict__ ws_cand,
        const int*   __restrict__ ws_cnt,
        float*       __restrict__ out) {
    __shared__ float    s_cand[CAP];
    __shared__ unsigned s_hist[NHIST];
    __shared__ int      s_ids[T_];
    __shared__ int      s_cnt;
    __shared__ int      s_bstar;
    __shared__ float    s_red[4];

    const int row = blockIdx.x;
    const int tid = threadIdx.x;
    const float* __restrict__ rp = sparse + (size_t)row * V_;

    if (tid < T_) s_ids[tid] = tids[row * T_ + tid];
    __syncthreads();

    // ---- target + margin losses (threads 0..15; rows are L2/L3-hot) ----
    if (tid < T_) {
        float x  = rp[s_ids[tid]];
        float tl = -logf(x + 1e-8f);
        float ml = fmaxf(1.0f - x, 0.0f);
        #pragma unroll
        for (int off = 8; off > 0; off >>= 1) {
            tl += __shfl_down(tl, off);
            ml += __shfl_down(ml, off);
        }
        if (tid == 0) {
            atomicAdd(out + 0, tl * (1.0f / (B_ * T_)));
            atomicAdd(out + 1, ml * (1.0f / (B_ * T_)));
        }
    }

    int cnt = ws_cnt[row];

    if (cnt >= TOPK_ && cnt <= CAP) {
        // normal path: pull candidates into LDS
        const float* cand = ws_cand + (size_t)row * CAP;
        for (int i = tid; i < cnt; i += 256) s_cand[i] = cand[i];
        __syncthreads();
    } else {
        // exact histogram fallback (never triggers for uniform data)
        for (int i = tid; i < NHIST; i += 256) s_hist[i] = 0u;
        if (tid == 0) s_cnt = 0;
        __syncthreads();
        const float4* rp4 = (const float4*)rp;
        for (int i = tid; i < NF4; i += 256) {
            float4 v = rp4[i];
            float xs[4] = {v.x, v.y, v.z, v.w};
            #pragma unroll
            for (int c = 0; c < 4; ++c) {
                int b = (int)(xs[c] * (float)NHIST);
                b = min(max(b, 0), NHIST - 1);
                atomicAdd(&s_hist[b], 1u);
            }
        }
        __syncthreads();
        if (tid == 0) {
            for (int j = 0; j < T_; ++j) {
                int id = s_ids[j];
                bool dup = false;
                for (int q = 0; q < j; ++q) dup = dup || (s_ids[q] == id);
                if (!dup) {
                    int b = (int)(rp[id] * (float)NHIST);
                    b = min(max(b, 0), NHIST - 1);
                    s_hist[b]--;
                }
            }
            int acc = 0, b = NHIST - 1;
            for (; b >= 0; --b) {
                acc += (int)s_hist[b];
                if (acc >= TOPK_) break;
            }
            s_bstar = max(b, 0);
        }
        __syncthreads();
        int bstar = s_bstar;
        for (int i = tid; i < NF4; i += 256) {
            float4 v = rp4[i];
            int col = i << 2;
            float xs[4] = {v.x, v.y, v.z, v.w};
            #pragma unroll
            for (int c = 0; c < 4; ++c) {
                float x = xs[c];
                int b = (int)(x * (float)NHIST);
                b = min(max(b, 0), NHIST - 1);
                if (b >= bstar) {
                    int cc = col + c;
                    bool is_t = false;
                    #pragma unroll
                    for (int j = 0; j < T_; ++j) is_t |= (cc == s_ids[j]);
                    if (!is_t) {
                        int k = atomicAdd(&s_cnt, 1);
                        if (k < CAP) s_cand[k] = x;
                    }
                }
            }
        }
        __syncthreads();
        cnt = min(s_cnt, CAP);
    }

    // ---- O(n^2) exact rank-select: include x_i iff rank < TOPK_.
    // rank = #{j: y_j > x_i} + #{j<i: y_j == x_i} (deterministic tie-break).
    // Inner loop index j is uniform across the wave -> LDS broadcast reads.
    float sum = 0.f;
    for (int i = tid; i < cnt; i += 256) {
        float x = s_cand[i];
        int rank = 0;
        for (int j = 0; j < cnt; ++j) {
            float y = s_cand[j];
            rank += (y > x) ? 1 : ((y == x && j < i) ? 1 : 0);
        }
        if (rank < TOPK_) sum += x;
    }

    // ---- block reduce (4 waves) ----
    #pragma unroll
    for (int off = 32; off > 0; off >>= 1) sum += __shfl_down(sum, off);
    if ((tid & 63) == 0) s_red[tid >> 6] = sum;
    __syncthreads();
    if (tid == 0) {
        float tot = s_red[0] + s_red[1] + s_red[2] + s_red[3];
        atomicAdd(out + 2, tot * (1.0f / (B_ * TOPK_)));
    }
}

extern "C" void kernel_launch(void* const* d_in, const int* in_sizes, int n_in,
                              void* d_out, int out_size, void* d_ws, size_t ws_size,
                              hipStream_t stream) {
    const float* sparse = (const float*)d_in[0];
    const int*   tids   = (const int*)d_in[1];
    float*       out    = (float*)d_out;
    int*         ws_cnt  = (int*)d_ws;
    float*       ws_cand = (float*)((char*)d_ws + 4096);

    zero_kernel<<<1, 256, 0, stream>>>(out, ws_cnt);
    collect_kernel<<<B_ * SLICES, 256, 0, stream>>>(sparse, tids, ws_cand, ws_cnt);
    reduce_kernel<<<B_, 256, 0, stream>>>(sparse, tids, ws_cand, ws_cnt, out);
}

// Round 3
// 218.597 us; speedup vs baseline: 1.1241x; 1.1241x over previous
//
#include <hip/hip_runtime.h>
#include <cstddef>
#include <cstdint>

// Problem constants (fixed by reference file)
#define B_      256
#define V_      128000
#define T_      16
#define TOPK_   100
#define NF4     (V_ / 4)        // 32000 float4 per row
#define NHIST   4096
#define SLICES  5
#define F4S     (NF4 / SLICES)  // 6400 float4 per slice (25 iters x 256 thr)
#define ITERS   (F4S / 256)     // 25
#define UNROLL  5
#define CAP_BLK 256             // per-block candidate cap (mean 51, 28 sigma)
#define CAP_ROW 2048            // >= SLICES*CAP_BLK = 1280
#define T0      0.998f          // expected ~256 candidates/row

// ws layout: [0,1024)      int ws_cnt[B_]
//            [1024,2048)   int ws_of[B_]      (overflow flags)
//            [4096,...)    float ws_cand[B_][CAP_ROW]   (2 MB)

__global__ void zero_kernel(float* o, int* ws_cnt, int* ws_of) {
    int t = threadIdx.x;
    if (t < 3) o[t] = 0.f;
    if (t < B_) { ws_cnt[t] = 0; ws_of[t] = 0; }
}

// Kernel A: streaming collect. 1280 blocks x 256 threads.
// Hot loop: 5 independent float4 loads in flight, hits staged via LDS atomic,
// ONE global atomic per block at the end.
__global__ __launch_bounds__(256) void collect_kernel(
        const float* __restrict__ sparse,
        const int*   __restrict__ tids,
        float*       __restrict__ ws_cand,
        int*         __restrict__ ws_cnt,
        int*         __restrict__ ws_of) {
    __shared__ int   s_ids[T_];
    __shared__ float s_buf[CAP_BLK];
    __shared__ int   s_n;
    __shared__ int   s_gbase;

    const int blk = blockIdx.x;
    const int row = blk / SLICES;
    const int sl  = blk - row * SLICES;
    const int tid = threadIdx.x;

    if (tid < T_) s_ids[tid] = tids[row * T_ + tid];
    if (tid == 0) s_n = 0;
    __syncthreads();

    const float4* __restrict__ rp4 = (const float4*)(sparse + (size_t)row * V_);
    const int base = sl * F4S + tid;

    for (int it = 0; it < ITERS; it += UNROLL) {
        float4 v[UNROLL];
        #pragma unroll
        for (int u = 0; u < UNROLL; ++u)
            v[u] = rp4[base + (it + u) * 256];
        #pragma unroll
        for (int u = 0; u < UNROLL; ++u) {
            const int col = (base + (it + u) * 256) << 2;
            float xs[4] = {v[u].x, v[u].y, v[u].z, v[u].w};
            #pragma unroll
            for (int c = 0; c < 4; ++c) {
                float x = xs[c];
                if (x >= T0) {
                    int cc = col + c;
                    bool is_t = false;
                    #pragma unroll
                    for (int j = 0; j < T_; ++j) is_t |= (cc == s_ids[j]);
                    if (!is_t) {
                        int k = atomicAdd(&s_n, 1);   // LDS atomic: ~64 cyc
                        if (k < CAP_BLK) s_buf[k] = x;
                    }
                }
            }
        }
    }
    __syncthreads();

    int n = min(s_n, CAP_BLK);
    if (tid == 0) {
        s_gbase = atomicAdd(ws_cnt + row, n);          // ONE global atomic/block
        if (s_n > CAP_BLK) atomicExch(ws_of + row, 1); // exactness guard
    }
    __syncthreads();
    int gbase = s_gbase;                                // gbase+n <= 1280 < CAP_ROW
    float* __restrict__ cand = ws_cand + (size_t)row * CAP_ROW;
    for (int i = tid; i < n; i += 256) cand[gbase + i] = s_buf[i];
}

// Kernel B: per-row top-100 via O(n^2) rank-select + target/margin losses.
__global__ __launch_bounds__(256) void reduce_kernel(
        const float* __restrict__ sparse,
        const int*   __restrict__ tids,
        const float* __restrict__ ws_cand,
        const int*   __restrict__ ws_cnt,
        const int*   __restrict__ ws_of,
        float*       __restrict__ out) {
    __shared__ float    s_cand[CAP_ROW];
    __shared__ unsigned s_hist[NHIST];
    __shared__ int      s_ids[T_];
    __shared__ int      s_cnt;
    __shared__ int      s_bstar;
    __shared__ float    s_red[4];

    const int row = blockIdx.x;
    const int tid = threadIdx.x;
    const float* __restrict__ rp = sparse + (size_t)row * V_;

    if (tid < T_) s_ids[tid] = tids[row * T_ + tid];
    __syncthreads();

    // ---- target + margin losses (threads 0..15; row is L2/L3-hot) ----
    if (tid < T_) {
        float x  = rp[s_ids[tid]];
        float tl = -logf(x + 1e-8f);
        float ml = fmaxf(1.0f - x, 0.0f);
        #pragma unroll
        for (int off = 8; off > 0; off >>= 1) {
            tl += __shfl_down(tl, off);
            ml += __shfl_down(ml, off);
        }
        if (tid == 0) {
            atomicAdd(out + 0, tl * (1.0f / (B_ * T_)));
            atomicAdd(out + 1, ml * (1.0f / (B_ * T_)));
        }
    }

    int cnt = ws_cnt[row];
    bool bad = (cnt < TOPK_) || (cnt > CAP_ROW) || (ws_of[row] != 0);

    if (!bad) {
        const float* cand = ws_cand + (size_t)row * CAP_ROW;
        for (int i = tid; i < cnt; i += 256) s_cand[i] = cand[i];
        __syncthreads();
    } else {
        // exact histogram fallback (astronomically rare for uniform data)
        for (int i = tid; i < NHIST; i += 256) s_hist[i] = 0u;
        if (tid == 0) s_cnt = 0;
        __syncthreads();
        const float4* rp4 = (const float4*)rp;
        for (int i = tid; i < NF4; i += 256) {
            float4 v = rp4[i];
            float xs[4] = {v.x, v.y, v.z, v.w};
            #pragma unroll
            for (int c = 0; c < 4; ++c) {
                int b = (int)(xs[c] * (float)NHIST);
                b = min(max(b, 0), NHIST - 1);
                atomicAdd(&s_hist[b], 1u);
            }
        }
        __syncthreads();
        if (tid == 0) {
            for (int j = 0; j < T_; ++j) {
                int id = s_ids[j];
                bool dup = false;
                for (int q = 0; q < j; ++q) dup = dup || (s_ids[q] == id);
                if (!dup) {
                    int b = (int)(rp[id] * (float)NHIST);
                    b = min(max(b, 0), NHIST - 1);
                    s_hist[b]--;
                }
            }
            int acc = 0, b = NHIST - 1;
            for (; b >= 0; --b) {
                acc += (int)s_hist[b];
                if (acc >= TOPK_) break;
            }
            s_bstar = max(b, 0);
        }
        __syncthreads();
        int bstar = s_bstar;
        for (int i = tid; i < NF4; i += 256) {
            float4 v = rp4[i];
            int col = i << 2;
            float xs[4] = {v.x, v.y, v.z, v.w};
            #pragma unroll
            for (int c = 0; c < 4; ++c) {
                float x = xs[c];
                int b = (int)(x * (float)NHIST);
                b = min(max(b, 0), NHIST - 1);
                if (b >= bstar) {
                    int cc = col + c;
                    bool is_t = false;
                    #pragma unroll
                    for (int j = 0; j < T_; ++j) is_t |= (cc == s_ids[j]);
                    if (!is_t) {
                        int k = atomicAdd(&s_cnt, 1);
                        if (k < CAP_ROW) s_cand[k] = x;
                    }
                }
            }
        }
        __syncthreads();
        cnt = min(s_cnt, CAP_ROW);
    }

    // ---- O(n^2) exact rank-select (n ~ 256): include x_i iff rank < TOPK_.
    // Inner index j is wave-uniform -> LDS broadcast, conflict-free.
    float sum = 0.f;
    for (int i = tid; i < cnt; i += 256) {
        float x = s_cand[i];
        int rank = 0;
        for (int j = 0; j < cnt; ++j) {
            float y = s_cand[j];
            rank += (y > x) ? 1 : ((y == x && j < i) ? 1 : 0);
        }
        if (rank < TOPK_) sum += x;
    }

    #pragma unroll
    for (int off = 32; off > 0; off >>= 1) sum += __shfl_down(sum, off);
    if ((tid & 63) == 0) s_red[tid >> 6] = sum;
    __syncthreads();
    if (tid == 0) {
        float tot = s_red[0] + s_red[1] + s_red[2] + s_red[3];
        atomicAdd(out + 2, tot * (1.0f / (B_ * TOPK_)));
    }
}

extern "C" void kernel_launch(void* const* d_in, const int* in_sizes, int n_in,
                              void* d_out, int out_size, void* d_ws, size_t ws_size,
                              hipStream_t stream) {
    const float* sparse = (const float*)d_in[0];
    const int*   tids   = (const int*)d_in[1];
    float*       out    = (float*)d_out;
    int*         ws_cnt  = (int*)d_ws;
    int*         ws_of   = (int*)((char*)d_ws + 1024);
    float*       ws_cand = (float*)((char*)d_ws + 4096);

    zero_kernel<<<1, 256, 0, stream>>>(out, ws_cnt, ws_of);
    collect_kernel<<<B_ * SLICES, 256, 0, stream>>>(sparse, tids, ws_cand, ws_cnt, ws_of);
    reduce_kernel<<<B_, 256, 0, stream>>>(sparse, tids, ws_cand, ws_cnt, ws_of, out);
}